// Round 22
// baseline (2972.170 us; speedup 1.0000x reference)
//
#include <hip/hip_runtime.h>

typedef _Float16 half2_t __attribute__((ext_vector_type(2)));

#define NB 64
#define NT 2048
#define ND 256
#define NH 256
#define NTHR 512
#define CHUNK 32
#define NCHUNK (NT / CHUNK)   // 64

// LDS (dword units). Producer: x-stage [32 t][132]. Consumer: hq dw 0..63,
// vq dw 64..127, azx f32[256] @128, ah0x f32[256] @384, ah1x f32[256] @640.
#define XT_STRIDE 132
#define LDS_DW (32 * XT_STRIDE + 16)
#define VQ_BYTE 256
#define AZX_OFF 128
#define AH0_OFF 384
#define AH1_OFF 640

__device__ __forceinline__ float sigmoid_f(float x) { return 1.f / (1.f + __expf(-x)); }
__device__ __forceinline__ float tanh_f(float x)    { return 1.f - 2.f / (1.f + __expf(2.f * x)); }
__device__ __forceinline__ half2_t mkh2(float a, float b) {
    half2_t r; r.x = (_Float16)a; r.y = (_Float16)b; return r;
}
__device__ __forceinline__ half2_t u2h2(unsigned u) { return __builtin_bit_cast(half2_t, u); }
__device__ __forceinline__ float h2get(unsigned u, int idx) {
    half2_t h = u2h2(u);
    return idx ? (float)h.y : (float)h.x;
}
__device__ __forceinline__ int dot4i8(int a, int b, int c) {
#if __has_builtin(__builtin_amdgcn_sdot4)
    return __builtin_amdgcn_sdot4(a, b, c, false);
#else
    int d;
    asm("v_dot4_i32_i8 %0, %1, %2, %3" : "=v"(d) : "v"(a), "v"(b), "v"(c));
    return d;
#endif
}
// barrier draining only LDS (lgkm); global loads/stores stay in flight.
#define BAR_LDS() asm volatile("s_waitcnt lgkmcnt(0)\n\ts_barrier" ::: "memory")

// Grid 256 x 512.
//  bid <  64 : consumer — GATE-SPLIT: group A (waves 0-3) = z full-k + h half-0
//              (96 weight dw); group B (waves 4-7) = r full-k + h half-1 (96 dw).
//              128-VGPR budget -> 2 waves/SIMD (TLP restored). h-gate partials
//              combined via conflict-free b32 LDS exchange (3 barriers/step).
//              Both groups redundantly compute the blend (identical fp32 state).
//  bid >= 64 : producer (gate g, batch b) — fp16 x-projections into ring
//              (R9's validated 512-thread version).
extern "C" __global__ void __launch_bounds__(NTHR)
gru_fused(const float* __restrict__ x,
          const float* __restrict__ Wz, const float* __restrict__ bz,
          const float* __restrict__ Wr, const float* __restrict__ br,
          const float* __restrict__ Wh, const float* __restrict__ bh,
          float* __restrict__ out,
          unsigned* prodflag, unsigned* consflag,
          unsigned long long* preZR, unsigned* preH, int ring)
{
    __shared__ __align__(16) unsigned smem[LDS_DW];
    const int tid = threadIdx.x;
    const int bid = blockIdx.x;
    const int rmask = ring - 1;

    if (bid >= NB) {
        // ---------------- producer (R9/R10 512-thread version) ----------------
        const int pb = bid - NB;        // 0..191
        const int g  = pb >> 6;         // 0=z 1=r 2=h
        const int b  = pb & 63;
        const float* W    = (g == 0) ? Wz : (g == 1) ? Wr : Wh;
        const float* bias = (g == 0) ? bz : (g == 1) ? br : bh;
        const int c  = tid >> 1;        // col 0..255
        const int kh = tid & 1;         // k-half of x part

        half2_t w2[64];                 // x-part rows kh*128..+127, col c
        #pragma unroll
        for (int j = 0; j < 64; ++j)
            w2[j] = mkh2(W[(kh * 128 + 2 * j) * NH + c],
                         W[(kh * 128 + 2 * j + 1) * NH + c]);
        const float bv = bias[c];

        for (int ch = 0; ch < NCHUNK; ++ch) {
            const int lead = ch * CHUNK + CHUNK - ring;
            if (lead > 0) {
                if (tid == 0) {
                    unsigned it = 0;
                    while ((int)__hip_atomic_load(&consflag[b], __ATOMIC_RELAXED,
                                                  __HIP_MEMORY_SCOPE_AGENT) < lead) {
                        __builtin_amdgcn_s_sleep(8);
                        if (++it > (1u << 20)) break;
                    }
                }
                __syncthreads();
            }
            const int t0 = ch * CHUNK;
            {   // stage x[b][t0..t0+31][:] into LDS as half2, row stride 132 dw
                const float4* xs = reinterpret_cast<const float4*>(
                    x + ((size_t)b * NT + t0) * ND);
                #pragma unroll
                for (int rep = 0; rep < 4; ++rep) {
                    const int f = rep * NTHR + tid;   // 0..2047 float4s
                    const float4 v = xs[f];
                    const int tt = f >> 6;
                    const int u2 = f & 63;
                    uint2 pk;
                    pk.x = __builtin_bit_cast(unsigned, mkh2(v.x, v.y));
                    pk.y = __builtin_bit_cast(unsigned, mkh2(v.z, v.w));
                    *reinterpret_cast<uint2*>(&smem[tt * XT_STRIDE + u2 * 2]) = pk;
                }
            }
            __syncthreads();
            #pragma unroll 1
            for (int t = 0; t < CHUNK; ++t) {
                const uint4* xr4 = reinterpret_cast<const uint4*>(
                    &smem[t * XT_STRIDE + kh * 64]);
                float a0 = 0.f, a1 = 0.f, a2 = 0.f, a3 = 0.f;
                #pragma unroll
                for (int i = 0; i < 16; ++i) {
                    const uint4 xv = xr4[i];
                    a0 = __builtin_amdgcn_fdot2(u2h2(xv.x), w2[i*4+0], a0, false);
                    a1 = __builtin_amdgcn_fdot2(u2h2(xv.y), w2[i*4+1], a1, false);
                    a2 = __builtin_amdgcn_fdot2(u2h2(xv.z), w2[i*4+2], a2, false);
                    a3 = __builtin_amdgcn_fdot2(u2h2(xv.w), w2[i*4+3], a3, false);
                }
                float a = (a0 + a1) + (a2 + a3);
                a += __shfl_xor(a, 1, 64);   // combine k-halves
                a += bv;
                const float an = __shfl_xor(a, 2, 64);  // partner col c^1
                if (!(tid & 3)) {            // kh==0 && c even
                    const unsigned pk = __builtin_bit_cast(unsigned, mkh2(a, an));
                    const size_t slot = (size_t)b * ring + ((t0 + t) & rmask);
                    if (g == 2) {
                        __hip_atomic_store(&preH[slot * 128 + (c >> 1)], pk,
                                           __ATOMIC_RELAXED, __HIP_MEMORY_SCOPE_AGENT);
                    } else {
                        unsigned* zr32 = reinterpret_cast<unsigned*>(&preZR[slot * 128 + (c >> 1)]);
                        __hip_atomic_store(&zr32[g], pk,
                                           __ATOMIC_RELAXED, __HIP_MEMORY_SCOPE_AGENT);
                    }
                }
            }
            asm volatile("s_waitcnt vmcnt(0)" ::: "memory");  // drain ring stores
            __syncthreads();
            if (tid == 0)
                __hip_atomic_store(&prodflag[b * 3 + g], (unsigned)(ch + 1),
                                   __ATOMIC_RELAXED, __HIP_MEMORY_SCOPE_AGENT);
            __syncthreads();
        }
        return;
    }

    // ---------------- consumer: gate-split recurrence for batch b ----------
    const int b    = bid;
    const int p    = tid >> 8;     // 0 = group A (z + h0), 1 = group B (r + h1)
    const int c    = tid & 255;    // column
    const int lane = tid & 63;
    const int sub  = c & 1;        // half of the packed pre col-pair

    // main gate (full k) + h-gate half weights, int8-quantized into regs
    const float* Wm = p ? Wr : Wz;
    float mxm = 1e-8f, mxh = 1e-8f;
    #pragma unroll 4
    for (int j = 0; j < 256; ++j) mxm = fmaxf(mxm, fabsf(Wm[(ND + j) * NH + c]));
    {
        const int kb = ND + p * 128;
        #pragma unroll 4
        for (int j = 0; j < 128; ++j) mxh = fmaxf(mxh, fabsf(Wh[(kb + j) * NH + c]));
    }
    const float qsm = 127.0f / mxm, qsh = 127.0f / mxh;
    const float deqm = mxm / (127.0f * 127.0f);
    const float deqh = mxh / (127.0f * 127.0f);

    uint4 wm4[16];   // main gate: 64 dw
    #pragma unroll
    for (int i = 0; i < 16; ++i) {
        unsigned d4[4];
        #pragma unroll
        for (int d = 0; d < 4; ++d) {
            unsigned a = 0;
            #pragma unroll
            for (int j = 0; j < 4; ++j) {
                const int k = ND + (i * 4 + d) * 4 + j;
                const int q = __float2int_rn(Wm[k * NH + c] * qsm);
                a |= ((unsigned)(q & 255)) << (8 * j);
            }
            d4[d] = a;
        }
        wm4[i] = make_uint4(d4[0], d4[1], d4[2], d4[3]);
    }
    uint4 wh4[8];    // h-gate half: 32 dw
    #pragma unroll
    for (int i = 0; i < 8; ++i) {
        unsigned d4[4];
        #pragma unroll
        for (int d = 0; d < 4; ++d) {
            unsigned a = 0;
            #pragma unroll
            for (int j = 0; j < 4; ++j) {
                const int k = ND + p * 128 + (i * 4 + d) * 4 + j;
                const int q = __float2int_rn(Wh[k * NH + c] * qsh);
                a |= ((unsigned)(q & 255)) << (8 * j);
            }
            d4[d] = a;
        }
        wh4[i] = make_uint4(d4[0], d4[1], d4[2], d4[3]);
    }

    if (tid < 128) smem[tid] = 0u;   // zero hq + vq (h0 = 0)
    float hreg = 0.f;                // duplicated in both groups (identical fp32)

    // wait for chunk 0 of all 3 gates
    if (tid < 3) {
        unsigned it = 0;
        while (__hip_atomic_load(&prodflag[b * 3 + tid], __ATOMIC_RELAXED,
                                 __HIP_MEMORY_SCOPE_AGENT) < 1u) {
            __builtin_amdgcn_s_sleep(8);
            if (++it > (1u << 20)) break;
        }
    }
    __syncthreads();

    const unsigned long long* zrb = preZR + (size_t)b * ring * 128 + (c >> 1);
    const unsigned*           hhb = preH  + (size_t)b * ring * 128 + (c >> 1);
    float* outb = out + (size_t)b * NT * NH + c;
    const uint4* hq4 = reinterpret_cast<const uint4*>(smem);
    const uint4* vq4 = reinterpret_cast<const uint4*>(
                           reinterpret_cast<const char*>(smem) + VQ_BYTE);
    char* hqb = reinterpret_cast<char*>(smem);
    float* azx  = reinterpret_cast<float*>(smem + AZX_OFF);
    float* ah0x = reinterpret_cast<float*>(smem + AH0_OFF);
    float* ah1x = reinterpret_cast<float*>(smem + AH1_OFF);

    unsigned long long zr_c = __hip_atomic_load(zrb, __ATOMIC_RELAXED, __HIP_MEMORY_SCOPE_AGENT);
    unsigned           hh_c = __hip_atomic_load(hhb, __ATOMIC_RELAXED, __HIP_MEMORY_SCOPE_AGENT);

    // one GRU step (gate-split, 3 barriers)
    auto step = [&](int t) {
        // ---- stage A: main-gate full-k dots (64 rl + 64 dots) ----
        const uint4 hvec = hq4[lane & 15];
        int a0 = 0, a1 = 0, a2 = 0, a3 = 0;
        #pragma unroll
        for (int i = 0; i < 16; ++i) {
            const int sx = __builtin_amdgcn_readlane((int)hvec.x, i);
            const int sy = __builtin_amdgcn_readlane((int)hvec.y, i);
            const int sz = __builtin_amdgcn_readlane((int)hvec.z, i);
            const int sw = __builtin_amdgcn_readlane((int)hvec.w, i);
            a0 = dot4i8(sx, (int)wm4[i].x, a0);
            a1 = dot4i8(sy, (int)wm4[i].y, a1);
            a2 = dot4i8(sz, (int)wm4[i].z, a2);
            a3 = dot4i8(sw, (int)wm4[i].w, a3);
        }
        const float pre_m = p ? h2get((unsigned)(zr_c >> 32), sub)
                              : h2get((unsigned)(zr_c & 0xffffffffu), sub);
        const float amf = (float)((a0 + a1) + (a2 + a3)) * deqm + pre_m;
        if (p) {   // group B: r -> v publish
            const float r = sigmoid_f(amf);
            const float v = r * hreg;
            hqb[VQ_BYTE + c] = (char)__float2int_rn(v * 127.0f);
        }
        BAR_LDS();   // vq ready

        // ---- stage B: h-gate half dots over v (32 rl + 32 dots) ----
        const uint4 vvec = vq4[lane & 15];
        int h0 = 0, h1 = 0, h2 = 0, h3 = 0;
        #pragma unroll
        for (int i = 0; i < 8; ++i) {
            const int li = p * 8 + i;   // group's k-half lives in lanes li
            const int sx = __builtin_amdgcn_readlane((int)vvec.x, li);
            const int sy = __builtin_amdgcn_readlane((int)vvec.y, li);
            const int sz = __builtin_amdgcn_readlane((int)vvec.z, li);
            const int sw = __builtin_amdgcn_readlane((int)vvec.w, li);
            h0 = dot4i8(sx, (int)wh4[i].x, h0);
            h1 = dot4i8(sy, (int)wh4[i].y, h1);
            h2 = dot4i8(sz, (int)wh4[i].z, h2);
            h3 = dot4i8(sw, (int)wh4[i].w, h3);
        }
        const float ahp = (float)((h0 + h1) + (h2 + h3)) * deqh;
        if (p) { ah1x[c] = ahp; }
        else   { ah0x[c] = ahp; azx[c] = amf; }
        BAR_LDS();   // partials ready

        // ---- finish: combine halves, blend (both groups, identical fp32) ----
        const float ahf = p ? (ah0x[c] + ahp) : (ahp + ah1x[c]);
        const float zf  = p ? azx[c] : amf;
        const float z = sigmoid_f(zf);
        const float hhat = tanh_f(ahf + h2get(hh_c, sub));
        const float hn = hreg + z * (hhat - hreg);   // |hn| <= 1
        hreg = hn;
        if (p) hqb[c] = (char)__float2int_rn(hn * 127.0f);  // B publishes h
        else   outb[(size_t)t * NH] = hn;                   // A stores out
        BAR_LDS();   // hq = h_t everywhere
    };
    auto prefetch = [&](int t, unsigned long long& zr_n, unsigned& hh_n) {
        const int so = (t & rmask) * 128;
        zr_n = __hip_atomic_load(zrb + so, __ATOMIC_RELAXED, __HIP_MEMORY_SCOPE_AGENT);
        hh_n = __hip_atomic_load(hhb + so, __ATOMIC_RELAXED, __HIP_MEMORY_SCOPE_AGENT);
    };

    // unrolled x4: chunk boundaries (t % 32 == 0) always land on group heads
    #pragma unroll 1
    for (int t = 0; t < NT; t += 4) {
        if (t && !(t & (CHUNK - 1))) {   // chunk boundary (1 in 8 groups)
            if (tid == 0)
                __hip_atomic_store(&consflag[b], (unsigned)t,
                                   __ATOMIC_RELAXED, __HIP_MEMORY_SCOPE_AGENT);
            const unsigned need = (unsigned)((t >> 5) + 1);
            if (tid < 3) {
                unsigned it = 0;
                while (__hip_atomic_load(&prodflag[b * 3 + tid], __ATOMIC_RELAXED,
                                         __HIP_MEMORY_SCOPE_AGENT) < need) {
                    __builtin_amdgcn_s_sleep(8);
                    if (++it > (1u << 20)) break;
                }
            }
            __syncthreads();
            prefetch(t, zr_c, hh_c);
        }
        unsigned long long zr_n; unsigned hh_n;
        prefetch(t + 1, zr_n, hh_n);
        step(t);
        zr_c = zr_n; hh_c = hh_n;
        prefetch(t + 2, zr_n, hh_n);
        step(t + 1);
        zr_c = zr_n; hh_c = hh_n;
        prefetch(t + 3, zr_n, hh_n);
        step(t + 2);
        zr_c = zr_n; hh_c = hh_n;
        const int t4 = t + 4;
        const bool pf4 = (t4 < NT) && ((t4 & (CHUNK - 1)) != 0);
        if (pf4) prefetch(t4, zr_n, hh_n);
        step(t + 3);
        if (pf4) { zr_c = zr_n; hh_c = hh_n; }
    }
}

extern "C" void kernel_launch(void* const* d_in, const int* in_sizes, int n_in,
                              void* d_out, int out_size, void* d_ws, size_t ws_size,
                              hipStream_t stream) {
    const float* x  = (const float*)d_in[0];
    const float* Wz = (const float*)d_in[1];
    const float* bz = (const float*)d_in[2];
    const float* Wr = (const float*)d_in[3];
    const float* br = (const float*)d_in[4];
    const float* Wh = (const float*)d_in[5];
    const float* bh = (const float*)d_in[6];
    float* outp = (float*)d_out;

    // ring sizing: per ring-step bytes = NB*128*12 = 96 KiB. Cap at 64 slots
    // (6 MB) so the rolling pre window stays L2/L3-hot.
    const size_t base = 4096;
    int ring = 32;
    for (int r = 64; r >= 32; r >>= 1) {
        const size_t need = base + (size_t)NB * r * 128 * 12;
        if (need <= ws_size) { ring = r; break; }
    }
    char* w = (char*)d_ws;
    unsigned* prodflag = (unsigned*)w;                 // [64][3]
    unsigned* consflag = (unsigned*)(w + 1024);        // [64]
    unsigned long long* preZR = (unsigned long long*)(w + base);          // [64][ring][128]
    unsigned* preH = (unsigned*)(w + base + (size_t)NB * ring * 128 * 8); // [64][ring][128]

    hipMemsetAsync(w, 0, 4096, stream);  // flags must start at 0 each launch
    gru_fused<<<256, NTHR, 0, stream>>>(x, Wz, bz, Wr, br, Wh, bh, outp,
                                        prodflag, consflag, preZR, preH, ring);
}

// Round 23
// 1899.840 us; speedup vs baseline: 1.5644x; 1.5644x over previous
//
#include <hip/hip_runtime.h>

typedef _Float16 half2_t __attribute__((ext_vector_type(2)));

#define NB 64
#define NT 2048
#define ND 256
#define NH 256
#define NTHR 256
#define CHUNK 32
#define NCHUNK (NT / CHUNK)   // 64

// LDS (dword units). Producer: x-stage [32 t][132]. Consumer: hq bytes 0..255
// (dw 0..63), vq bytes 256..511 (dw 64..127).
#define XT_STRIDE 132
#define LDS_DW (32 * XT_STRIDE + 16)
#define VQ_BYTE 256

__device__ __forceinline__ float sigmoid_f(float x) { return 1.f / (1.f + __expf(-x)); }
__device__ __forceinline__ float tanh_f(float x)    { return 1.f - 2.f / (1.f + __expf(2.f * x)); }
__device__ __forceinline__ half2_t mkh2(float a, float b) {
    half2_t r; r.x = (_Float16)a; r.y = (_Float16)b; return r;
}
__device__ __forceinline__ half2_t u2h2(unsigned u) { return __builtin_bit_cast(half2_t, u); }
__device__ __forceinline__ float h2get(unsigned u, int idx) {
    half2_t h = u2h2(u);
    return idx ? (float)h.y : (float)h.x;
}
__device__ __forceinline__ int dot4i8(int a, int b, int c) {
#if __has_builtin(__builtin_amdgcn_sdot4)
    return __builtin_amdgcn_sdot4(a, b, c, false);
#else
    int d;
    asm("v_dot4_i32_i8 %0, %1, %2, %3" : "=v"(d) : "v"(a), "v"(b), "v"(c));
    return d;
#endif
}
// barrier draining only LDS (lgkm); global loads/stores stay in flight.
#define BAR_LDS() asm volatile("s_waitcnt lgkmcnt(0)\n\ts_barrier" ::: "memory")

// Grid 256 x 256 — SESSION CHAMPION (R21 structure, reverted after R22's
// gate-split regression). 40.4ms -> 1.90ms over the session (21.3x).
//  bid <  64 : consumer — batch b, ONE column per thread, full k=256; all 3
//              gates int8 in VGPRs (192 dw; 256-reg budget at 256 thr =>
//              1 wave/SIMD). h/v exchanged via 1 cooperative ds_read_b128 +
//              readlane->SGPR broadcast (zero VGPR pressure). Unroll x4,
//              rolling 1-ahead pre-activation prefetch, ring-64 (L2-hot),
//              z-sigmoid deferred past the v-barrier.
//  bid >= 64 : producer (gate g, batch b) — fp16 x-projections into ring,
//              RELAXED agent atomics + vmcnt drain before flag store.
extern "C" __global__ void __launch_bounds__(NTHR)
gru_fused(const float* __restrict__ x,
          const float* __restrict__ Wz, const float* __restrict__ bz,
          const float* __restrict__ Wr, const float* __restrict__ br,
          const float* __restrict__ Wh, const float* __restrict__ bh,
          float* __restrict__ out,
          unsigned* prodflag, unsigned* consflag,
          unsigned long long* preZR, unsigned* preH, int ring)
{
    __shared__ __align__(16) unsigned smem[LDS_DW];
    const int tid = threadIdx.x;
    const int bid = blockIdx.x;
    const int rmask = ring - 1;

    if (bid >= NB) {
        // ---------------- producer ----------------
        const int pb = bid - NB;        // 0..191
        const int g  = pb >> 6;         // 0=z 1=r 2=h
        const int b  = pb & 63;
        const float* W    = (g == 0) ? Wz : (g == 1) ? Wr : Wh;
        const float* bias = (g == 0) ? bz : (g == 1) ? br : bh;
        const int kh = tid & 1;         // k-half (128 x-inputs)
        const int c2 = tid >> 1;        // col-pair 0..127
        const int c0 = c2 * 2, c1 = c0 + 1;

        half2_t wa[64], wb[64];         // x-part rows kh*128..+127, cols c0,c1
        #pragma unroll
        for (int j = 0; j < 64; ++j) {
            const int k = kh * 128 + 2 * j;
            wa[j] = mkh2(W[k * NH + c0], W[(k + 1) * NH + c0]);
            wb[j] = mkh2(W[k * NH + c1], W[(k + 1) * NH + c1]);
        }
        const float bv0 = bias[c0], bv1 = bias[c1];

        for (int ch = 0; ch < NCHUNK; ++ch) {
            const int lead = ch * CHUNK + CHUNK - ring;
            if (lead > 0) {
                if (tid == 0) {
                    unsigned it = 0;
                    while ((int)__hip_atomic_load(&consflag[b], __ATOMIC_RELAXED,
                                                  __HIP_MEMORY_SCOPE_AGENT) < lead) {
                        __builtin_amdgcn_s_sleep(8);
                        if (++it > (1u << 20)) break;
                    }
                }
                __syncthreads();
            }
            const int t0 = ch * CHUNK;
            {   // stage x[b][t0..t0+31][:] into LDS as half2, row stride 132 dw
                const float4* xs = reinterpret_cast<const float4*>(
                    x + (size_t)b * NT * ND + (size_t)t0 * ND);
                #pragma unroll
                for (int rep = 0; rep < 8; ++rep) {
                    const int f = rep * NTHR + tid;     // 0..2047 float4s
                    const float4 v = xs[f];
                    const int tt = f >> 6;
                    const int u2 = f & 63;
                    uint2 pk;
                    pk.x = __builtin_bit_cast(unsigned, mkh2(v.x, v.y));
                    pk.y = __builtin_bit_cast(unsigned, mkh2(v.z, v.w));
                    *reinterpret_cast<uint2*>(&smem[tt * XT_STRIDE + u2 * 2]) = pk;
                }
            }
            __syncthreads();
            #pragma unroll 1
            for (int t = 0; t < CHUNK; ++t) {
                const uint4* xr4 = reinterpret_cast<const uint4*>(
                    &smem[t * XT_STRIDE + kh * 64]);
                float a00 = 0.f, a01 = 0.f, a10 = 0.f, a11 = 0.f;
                #pragma unroll
                for (int i = 0; i < 16; ++i) {
                    const uint4 xv = xr4[i];
                    a00 = __builtin_amdgcn_fdot2(u2h2(xv.x), wa[i*4+0], a00, false);
                    a01 = __builtin_amdgcn_fdot2(u2h2(xv.y), wa[i*4+1], a01, false);
                    a00 = __builtin_amdgcn_fdot2(u2h2(xv.z), wa[i*4+2], a00, false);
                    a01 = __builtin_amdgcn_fdot2(u2h2(xv.w), wa[i*4+3], a01, false);
                    a10 = __builtin_amdgcn_fdot2(u2h2(xv.x), wb[i*4+0], a10, false);
                    a11 = __builtin_amdgcn_fdot2(u2h2(xv.y), wb[i*4+1], a11, false);
                    a10 = __builtin_amdgcn_fdot2(u2h2(xv.z), wb[i*4+2], a10, false);
                    a11 = __builtin_amdgcn_fdot2(u2h2(xv.w), wb[i*4+3], a11, false);
                }
                float a0 = a00 + a01, a1 = a10 + a11;
                a0 += __shfl_xor(a0, 1, 64);   // combine k-halves (lane pairs)
                a1 += __shfl_xor(a1, 1, 64);
                a0 += bv0; a1 += bv1;
                if (kh == 0) {
                    const unsigned pk = __builtin_bit_cast(unsigned, mkh2(a0, a1));
                    const size_t slot = (size_t)b * ring + ((t0 + t) & rmask);
                    if (g == 2) {
                        __hip_atomic_store(&preH[slot * 128 + c2], pk,
                                           __ATOMIC_RELAXED, __HIP_MEMORY_SCOPE_AGENT);
                    } else {
                        unsigned* zr32 = reinterpret_cast<unsigned*>(&preZR[slot * 128 + c2]);
                        __hip_atomic_store(&zr32[g], pk,
                                           __ATOMIC_RELAXED, __HIP_MEMORY_SCOPE_AGENT);
                    }
                }
            }
            asm volatile("s_waitcnt vmcnt(0)" ::: "memory");  // drain ring stores
            __syncthreads();
            if (tid == 0)
                __hip_atomic_store(&prodflag[b * 3 + g], (unsigned)(ch + 1),
                                   __ATOMIC_RELAXED, __HIP_MEMORY_SCOPE_AGENT);
            __syncthreads();
        }
        return;
    }

    // ---------------- consumer: recurrence for batch b ----------------
    const int b    = bid;
    const int c    = tid;          // column 0..255 (one per thread)
    const int lane = tid & 63;
    const int sub  = c & 1;        // half of the packed pre col-pair

    // per-thread per-gate max |w| over the full 256-k column -> quant scales
    float mxz = 1e-8f, mxr = 1e-8f, mxh = 1e-8f;
    #pragma unroll 4
    for (int j = 0; j < 256; ++j) {
        mxz = fmaxf(mxz, fabsf(Wz[(ND + j) * NH + c]));
        mxr = fmaxf(mxr, fabsf(Wr[(ND + j) * NH + c]));
        mxh = fmaxf(mxh, fabsf(Wh[(ND + j) * NH + c]));
    }
    const float qsz = 127.0f / mxz, qsr = 127.0f / mxr, qsh = 127.0f / mxh;
    const float deqz = mxz / (127.0f * 127.0f);
    const float deqr = mxr / (127.0f * 127.0f);
    const float deqh = mxh / (127.0f * 127.0f);

    // quantize + pack: 16 uint4 per gate = 192 VGPRs
    uint4 wz4[16], wr4[16], wh4[16];
    #pragma unroll
    for (int i = 0; i < 16; ++i) {
        unsigned dz[4], dr[4], dh[4];
        #pragma unroll
        for (int d = 0; d < 4; ++d) {
            unsigned az = 0, ar = 0, ah = 0;
            #pragma unroll
            for (int j = 0; j < 4; ++j) {
                const int k = ND + (i * 4 + d) * 4 + j;
                const int qz = __float2int_rn(Wz[k * NH + c] * qsz);
                const int qr = __float2int_rn(Wr[k * NH + c] * qsr);
                const int qh = __float2int_rn(Wh[k * NH + c] * qsh);
                az |= ((unsigned)(qz & 255)) << (8 * j);
                ar |= ((unsigned)(qr & 255)) << (8 * j);
                ah |= ((unsigned)(qh & 255)) << (8 * j);
            }
            dz[d] = az; dr[d] = ar; dh[d] = ah;
        }
        wz4[i] = make_uint4(dz[0], dz[1], dz[2], dz[3]);
        wr4[i] = make_uint4(dr[0], dr[1], dr[2], dr[3]);
        wh4[i] = make_uint4(dh[0], dh[1], dh[2], dh[3]);
    }

    if (tid < 128) smem[tid] = 0u;   // zero hq + vq (h0 = 0)
    float hreg = 0.f;

    // wait for chunk 0 of all 3 gates
    if (tid < 3) {
        unsigned it = 0;
        while (__hip_atomic_load(&prodflag[b * 3 + tid], __ATOMIC_RELAXED,
                                 __HIP_MEMORY_SCOPE_AGENT) < 1u) {
            __builtin_amdgcn_s_sleep(8);
            if (++it > (1u << 20)) break;
        }
    }
    __syncthreads();

    const unsigned long long* zrb = preZR + (size_t)b * ring * 128 + (c >> 1);
    const unsigned*           hhb = preH  + (size_t)b * ring * 128 + (c >> 1);
    float* outb = out + (size_t)b * NT * NH + c;
    const uint4* hq4 = reinterpret_cast<const uint4*>(smem);
    const uint4* vq4 = reinterpret_cast<const uint4*>(
                           reinterpret_cast<const char*>(smem) + VQ_BYTE);
    char* hqb = reinterpret_cast<char*>(smem);

    unsigned long long zr_c = __hip_atomic_load(zrb, __ATOMIC_RELAXED, __HIP_MEMORY_SCOPE_AGENT);
    unsigned           hh_c = __hip_atomic_load(hhb, __ATOMIC_RELAXED, __HIP_MEMORY_SCOPE_AGENT);

    // one GRU step: consumes (zr_c, hh_c), updates hreg, publishes v then h.
    // z and r dot-chains SHARE one readlane set.
    auto step = [&](int t) {
        // ---- stage A: z, r int8 dots (h via 1 ds_read + readlane->SGPR) ----
        const uint4 hvec = hq4[lane & 15];    // one cooperative b128 per wave
        int az0 = 0, az1 = 0, az2 = 0, az3 = 0;
        int ar0 = 0, ar1 = 0, ar2 = 0, ar3 = 0;
        #pragma unroll
        for (int i = 0; i < 16; ++i) {
            const int sx = __builtin_amdgcn_readlane((int)hvec.x, i);
            const int sy = __builtin_amdgcn_readlane((int)hvec.y, i);
            const int sz = __builtin_amdgcn_readlane((int)hvec.z, i);
            const int sw = __builtin_amdgcn_readlane((int)hvec.w, i);
            az0 = dot4i8(sx, (int)wz4[i].x, az0);
            az1 = dot4i8(sy, (int)wz4[i].y, az1);
            az2 = dot4i8(sz, (int)wz4[i].z, az2);
            az3 = dot4i8(sw, (int)wz4[i].w, az3);
            ar0 = dot4i8(sx, (int)wr4[i].x, ar0);
            ar1 = dot4i8(sy, (int)wr4[i].y, ar1);
            ar2 = dot4i8(sz, (int)wr4[i].z, ar2);
            ar3 = dot4i8(sw, (int)wr4[i].w, ar3);
        }
        // raw z pre-act; sigmoid deferred past the barrier
        const float azf = (float)((az0 + az1) + (az2 + az3)) * deqz
                        + h2get((unsigned)(zr_c & 0xffffffffu), sub);
        const float arf = (float)((ar0 + ar1) + (ar2 + ar3)) * deqr;
        const float r = sigmoid_f(arf + h2get((unsigned)(zr_c >> 32), sub));
        const float v = r * hreg;
        hqb[VQ_BYTE + c] = (char)__float2int_rn(v * 127.0f);   // publish v[c] int8
        BAR_LDS();   // vq ready

        // ---- stage B: h_hat dot over v; z-sigmoid in the shadow ----
        const float z = sigmoid_f(azf);
        const uint4 vvec = vq4[lane & 15];
        int ah0 = 0, ah1 = 0, ah2 = 0, ah3 = 0;
        #pragma unroll
        for (int i = 0; i < 16; ++i) {
            const int sx = __builtin_amdgcn_readlane((int)vvec.x, i);
            const int sy = __builtin_amdgcn_readlane((int)vvec.y, i);
            const int sz = __builtin_amdgcn_readlane((int)vvec.z, i);
            const int sw = __builtin_amdgcn_readlane((int)vvec.w, i);
            ah0 = dot4i8(sx, (int)wh4[i].x, ah0);
            ah1 = dot4i8(sy, (int)wh4[i].y, ah1);
            ah2 = dot4i8(sz, (int)wh4[i].z, ah2);
            ah3 = dot4i8(sw, (int)wh4[i].w, ah3);
        }
        const float ahf = (float)((ah0 + ah1) + (ah2 + ah3)) * deqh;
        const float hhat = tanh_f(ahf + h2get(hh_c, sub));
        const float hn = hreg + z * (hhat - hreg);   // |hn| <= 1
        hreg = hn;
        hqb[c] = (char)__float2int_rn(hn * 127.0f);  // publish h[c] first
        outb[(size_t)t * NH] = hn;                   // out-store off the barrier path
        BAR_LDS();   // hq = h_t everywhere
    };
    auto prefetch = [&](int t, unsigned long long& zr_n, unsigned& hh_n) {
        const int so = (t & rmask) * 128;
        zr_n = __hip_atomic_load(zrb + so, __ATOMIC_RELAXED, __HIP_MEMORY_SCOPE_AGENT);
        hh_n = __hip_atomic_load(hhb + so, __ATOMIC_RELAXED, __HIP_MEMORY_SCOPE_AGENT);
    };

    // unrolled x4: chunk boundaries (t % 32 == 0) always land on group heads
    #pragma unroll 1
    for (int t = 0; t < NT; t += 4) {
        if (t && !(t & (CHUNK - 1))) {   // chunk boundary (1 in 8 groups)
            if (tid == 0)
                __hip_atomic_store(&consflag[b], (unsigned)t,
                                   __ATOMIC_RELAXED, __HIP_MEMORY_SCOPE_AGENT);
            const unsigned need = (unsigned)((t >> 5) + 1);
            if (tid < 3) {
                unsigned it = 0;
                while (__hip_atomic_load(&prodflag[b * 3 + tid], __ATOMIC_RELAXED,
                                         __HIP_MEMORY_SCOPE_AGENT) < need) {
                    __builtin_amdgcn_s_sleep(8);
                    if (++it > (1u << 20)) break;
                }
            }
            __syncthreads();
            prefetch(t, zr_c, hh_c);
        }
        unsigned long long zr_n; unsigned hh_n;
        // steps t, t+1, t+2 with rolling 1-ahead prefetch (never boundaries)
        prefetch(t + 1, zr_n, hh_n);
        step(t);
        zr_c = zr_n; hh_c = hh_n;
        prefetch(t + 2, zr_n, hh_n);
        step(t + 1);
        zr_c = zr_n; hh_c = hh_n;
        prefetch(t + 3, zr_n, hh_n);
        step(t + 2);
        zr_c = zr_n; hh_c = hh_n;
        // step t+3: prefetch t+4 only if not a chunk boundary (else post-poll)
        const int t4 = t + 4;
        const bool pf4 = (t4 < NT) && ((t4 & (CHUNK - 1)) != 0);
        if (pf4) prefetch(t4, zr_n, hh_n);
        step(t + 3);
        if (pf4) { zr_c = zr_n; hh_c = hh_n; }
    }
}

extern "C" void kernel_launch(void* const* d_in, const int* in_sizes, int n_in,
                              void* d_out, int out_size, void* d_ws, size_t ws_size,
                              hipStream_t stream) {
    const float* x  = (const float*)d_in[0];
    const float* Wz = (const float*)d_in[1];
    const float* bz = (const float*)d_in[2];
    const float* Wr = (const float*)d_in[3];
    const float* br = (const float*)d_in[4];
    const float* Wh = (const float*)d_in[5];
    const float* bh = (const float*)d_in[6];
    float* outp = (float*)d_out;

    // ring sizing: per ring-step bytes = NB*128*12 = 96 KiB. Cap at 64 slots
    // (6 MB) so the rolling pre window stays L2/L3-hot.
    const size_t base = 4096;
    int ring = 32;
    for (int r = 64; r >= 32; r >>= 1) {
        const size_t need = base + (size_t)NB * r * 128 * 12;
        if (need <= ws_size) { ring = r; break; }
    }
    char* w = (char*)d_ws;
    unsigned* prodflag = (unsigned*)w;                 // [64][3]
    unsigned* consflag = (unsigned*)(w + 1024);        // [64]
    unsigned long long* preZR = (unsigned long long*)(w + base);          // [64][ring][128]
    unsigned* preH = (unsigned*)(w + base + (size_t)NB * ring * 128 * 8); // [64][ring][128]

    hipMemsetAsync(w, 0, 4096, stream);  // flags must start at 0 each launch
    gru_fused<<<256, NTHR, 0, stream>>>(x, Wz, bz, Wr, br, Wh, bh, outp,
                                        prodflag, consflag, preZR, preH, ring);
}